// Round 1
// 109.684 us; speedup vs baseline: 1.1496x; 1.1496x over previous
//
#include <hip/hip_runtime.h>
#include <math.h>
#include <stdint.h>

#define NM 8          // nmul
#define NPAR 12
#define PFD 8         // prefetch depth in timesteps (rolling register buffer)

typedef float v2f __attribute__((ext_vector_type(2)));

static __device__ __forceinline__ v2f v2min(v2f a, v2f b){ v2f r; r.x=fminf(a.x,b.x); r.y=fminf(a.y,b.y); return r; }
static __device__ __forceinline__ v2f v2max(v2f a, v2f b){ v2f r; r.x=fmaxf(a.x,b.x); r.y=fmaxf(a.y,b.y); return r; }
static __device__ __forceinline__ v2f v2minس(v2f a, float b){ v2f r; r.x=fminf(a.x,b); r.y=fminf(a.y,b); return r; }
static __device__ __forceinline__ v2f v2maxs(v2f a, float b){ v2f r; r.x=fmaxf(a.x,b); r.y=fmaxf(a.y,b); return r; }

__global__ __launch_bounds__(64) void hbv_kernel(
    const float* __restrict__ x,      // [T, G, 3]  (prcp, tmean, pet)
    const float* __restrict__ praw,   // [1, G, 12, NM] in [0,1)
    float* __restrict__ out,          // [T, G, NM]
    int G, int T)
{
    const int tid = blockIdx.x * blockDim.x + threadIdx.x;
    const int npair = G * (NM / 2);          // 2 chains (m, m+1) per thread
    if (tid >= npair) return;
    const int g  = tid >> 2;                 // / (NM/2)
    const int mp = (tid & 3) << 1;           // m0 = 0,2,4,6

    // Parameter bounds: BETA, FC, K0, K1, K2, LP, PERC, UZL, TT, CFMAX, CFR, CWH
    const float lb[NPAR] = {1.0f, 50.0f, 0.05f, 0.01f, 0.001f, 0.2f, 0.0f, 0.0f, -2.5f, 0.5f, 0.0f, 0.0f};
    const float ub[NPAR] = {6.0f, 1000.0f, 0.9f, 0.5f, 0.2f, 1.0f, 10.0f, 100.0f, 2.5f, 10.0f, 0.1f, 0.2f};

    v2f p[NPAR];
    const float* pr = praw + (size_t)g * (NPAR * NM) + mp;
    #pragma unroll
    for (int i = 0; i < NPAR; ++i) {
        v2f r = *(const v2f*)(pr + i * NM);  // 8B-aligned: mp is even
        p[i] = r * (ub[i] - lb[i]) + lb[i];
    }

    const v2f BETA = p[0], FC = p[1], K0 = p[2], K1 = p[3], K2 = p[4], LP = p[5],
              PERCc = p[6], UZL = p[7], TT = p[8], CFMAX = p[9], CFR = p[10], CWH = p[11];

    const v2f one = {1.0f, 1.0f};
    const v2f invFC        = one / FC;
    const v2f invLPFC      = one / (LP * FC);
    const v2f CFMAX_TT     = CFMAX * TT;       // fma-folded constants
    const v2f CFRCFMAX     = CFR * CFMAX;
    const v2f CFRCFMAX_TT  = CFRCFMAX * TT;

    v2f SNOWPACK = {0.001f, 0.001f}, MELTWATER = {0.001f, 0.001f},
        SM = {0.001f, 0.001f}, SUZ = {0.001f, 0.001f}, SLZ = {0.001f, 0.001f};

    // 32-bit byte offsets from uniform (SGPR) bases -> saddr-form loads/stores
    const char* xb = (const char*)x;
    char* ob = (char*)out;
    const uint32_t xstep = (uint32_t)G * 12u;                 // bytes per timestep in x
    const uint32_t xoff0 = (uint32_t)g * 12u;
    const uint32_t xmax  = xoff0 + (uint32_t)(T - 1) * xstep; // clamp target (last valid row)
    uint32_t ooff = (uint32_t)(g * NM + mp) * 4u;             // 8B-aligned (mp even)
    const uint32_t ostep = (uint32_t)(G * NM) * 4u;

    // --- prime the PFD-deep rolling forcing buffer (registers; static indices) ---
    float Pb[PFD], Tb[PFD], Eb[PFD];
    uint32_t poff = xoff0;
    #pragma unroll
    for (int d = 0; d < PFD; ++d) {
        Pb[d] = *(const float*)(xb + poff);
        Tb[d] = *(const float*)(xb + poff + 4);
        Eb[d] = *(const float*)(xb + poff + 8);
        uint32_t nx = poff + xstep;
        poff = (nx < xmax) ? nx : xmax;      // branch-free clamp, v_add + v_min_u32
    }

    auto step = [&](float P, float Tt, float PET) -> v2f {
        // --- snow routine ---
        v2f RAIN;
        RAIN.x = (Tt >= TT.x) ? P : 0.0f;
        RAIN.y = (Tt >= TT.y) ? P : 0.0f;
        SNOWPACK += (P - RAIN);                                    // SNOW
        v2f melt = v2min(v2maxs(CFMAX * Tt - CFMAX_TT, 0.0f), SNOWPACK);
        MELTWATER += melt;
        SNOWPACK  -= melt;
        v2f refr = v2min(v2maxs(CFRCFMAX_TT - CFRCFMAX * Tt, 0.0f), MELTWATER);
        SNOWPACK  += refr;
        MELTWATER -= refr;
        v2f tosoil = v2maxs(MELTWATER - CWH * SNOWPACK, 0.0f);
        MELTWATER -= tosoil;

        // --- soil routine ---
        v2f ratio = SM * invFC;                                    // > 0 always
        v2f bl;
        bl.x = BETA.x * __builtin_amdgcn_logf(ratio.x);            // log2
        bl.y = BETA.y * __builtin_amdgcn_logf(ratio.y);
        v2f sw;
        sw.x = __builtin_amdgcn_exp2f(bl.x);
        sw.y = __builtin_amdgcn_exp2f(bl.y);
        sw = v2minس(sw, 1.0f);
        v2f rt = RAIN + tosoil;
        v2f recharge = rt * sw;
        SM = SM + rt - recharge;
        v2f excess = v2maxs(SM - FC, 0.0f);
        SM -= excess;
        v2f evap  = v2minس(SM * invLPFC, 1.0f);
        v2f ETact = v2min(SM, PET * evap);
        SM = v2maxs(SM - ETact, 1e-5f);

        // --- response routine ---
        SUZ = SUZ + recharge + excess;
        v2f PERC = v2min(SUZ, PERCc);
        SUZ -= PERC;
        v2f Q0 = K0 * v2maxs(SUZ - UZL, 0.0f);
        SUZ -= Q0;
        v2f Q1 = K1 * SUZ;
        SUZ -= Q1;
        SLZ += PERC;
        v2f Q2 = K2 * SLZ;
        SLZ -= Q2;
        return Q0 + Q1 + Q2;
    };

    // --- main loop: unguarded, unrolled by PFD; consume slot d then refill for t+PFD ---
    int tb = 0;
    for (; tb + PFD <= T; tb += PFD) {
        #pragma unroll
        for (int d = 0; d < PFD; ++d) {
            const float P = Pb[d], Tt = Tb[d], PET = Eb[d];
            Pb[d] = *(const float*)(xb + poff);
            Tb[d] = *(const float*)(xb + poff + 4);
            Eb[d] = *(const float*)(xb + poff + 8);
            uint32_t nx = poff + xstep;
            poff = (nx < xmax) ? nx : xmax;
            v2f Q = step(P, Tt, PET);
            *(v2f*)(ob + ooff) = Q;          // dwordx2 store (both chains)
            ooff += ostep;
        }
    }
    // --- tail: 0..PFD-1 guarded steps, static slot indices ---
    #pragma unroll
    for (int d = 0; d < PFD; ++d) {
        if (tb + d < T) {
            v2f Q = step(Pb[d], Tb[d], Eb[d]);
            *(v2f*)(ob + ooff) = Q;
            ooff += ostep;
        }
    }
}

extern "C" void kernel_launch(void* const* d_in, const int* in_sizes, int n_in,
                              void* d_out, int out_size, void* d_ws, size_t ws_size,
                              hipStream_t stream) {
    const float* x    = (const float*)d_in[0];   // [T, G, 3]
    const float* praw = (const float*)d_in[1];   // [1, G, 12, 8]
    float* out = (float*)d_out;                  // [T, G, 8]

    const int G = in_sizes[1] / (NPAR * NM);     // 4000
    const int T = in_sizes[0] / (3 * G);         // 730

    const int npair = G * (NM / 2);              // 16000 threads, 2 chains each
    const int block = 64;
    const int grid = (npair + block - 1) / block;
    hbv_kernel<<<grid, block, 0, stream>>>(x, praw, out, G, T);
}